// Round 3
// baseline (561.953 us; speedup 1.0000x reference)
//
#include <hip/hip_runtime.h>

// CrossEntropyLoss_37254546326109 — fused CE + VAR + Inter + Center loss.
// logit [8,21,512,512] f32, target [8,1,512,512] i32, features [8,262144,32] f32.
// loss = (CE + 1.0*VAR + 0.5*Inter + 0.1*Center)/8, scalar f32 output.
//
// R1 lesson: fp32 atomics = CAS loops; zero fp32 atomics anywhere.
// R2 lesson: VGPR_Count=64 with 84+ floats of mandatory accumulator state +
//   ~52 MB phantom WRITE_SIZE = float4 acc[21] lived in SCRATCH. Both the
//   register-prefetch (R1) and LDS-pipeline (R2) versions were bound by
//   scratch RMW on the accumulators, not by load latency. Occupancy was also
//   grid-capped at 4 blocks/CU (16 waves).
// R3: (a) even/odd class split: 512 thr = 32 px-steps x 8 dim-groups x
//   2 class-halves; each thread owns 11 classes as ELEVEN NAMED float4
//   accumulators (no arrays -> cannot be demoted to scratch). (b) full
//   occupancy: 512-thr blocks, launch_bounds(512,8) -> VGPR cap 256,
//   32 waves/CU. (c) Phase A issues all 21 channel loads up front.
//   (d) Phase B keeps counted-vmcnt LDS double-buffer (stage 1 op/tile,
//   vmcnt(1) in-loop, vmcnt(0) only at the end).

constexpr int   N_IMG  = 8;
constexpr int   C_CLS  = 21;
constexpr int   P_PIX  = 512 * 512;     // pixels per image
constexpr int   PQ     = P_PIX / 4;     // float4-quads per image per channel
constexpr int   IGN    = 255;
constexpr float ALPHA  = 1.0f, BETA = 0.5f, GAMMA = 0.1f;

constexpr int MAIN_BLOCKS = 1024;   // 128 per image, 2048 px each
constexpr int PX_BLK      = 2048;   // pixels per block
constexpr int TILE_PX     = 64;     // feature pixels per LDS tile (8 KB)
constexpr int NT          = PX_BLK / TILE_PX;   // 32 tiles

// Workspace layout (4-byte units). Total ~2.9 MB. (unchanged from R2)
constexpr int OFF_PIX  = 0;                               // [1024][4] f32
constexpr int OFF_SSQ  = OFF_PIX + MAIN_BLOCKS * 4;       // [1024]    f32
constexpr int OFF_CLS  = OFF_SSQ + MAIN_BLOCKS;           // [1024][672] f32
constexpr int OFF_CNT  = OFF_CLS + MAIN_BLOCKS * 672;     // [1024][21] i32
constexpr int OFF_MEAN = OFF_CNT + MAIN_BLOCKS * C_CLS;   // [168] f32

// async global->LDS, 16 B per lane. LDS dest is wave-uniform base + lane*16.
__device__ __forceinline__ void gl_lds16(const float* g, void* l)
{
    __builtin_amdgcn_global_load_lds(
        (const __attribute__((address_space(1))) void*)g,
        (__attribute__((address_space(3))) void*)l, 16, 0, 0);
}

// ---------------------------------------------------------------------------
// Fused kernel. 512 threads.
// Phase A: thread = 4 pixels (one int4 of labels, float4 logit loads at
// channel stride PQ -> coalesced). All 21 channel loads issued up front
// (21 KB/wave in flight). Labels deposited to LDS for Phase B.
// Phase B: 512 thr = 32 px-steps x 8 dim-groups x 2 class-halves. Feature
// tiles (64 px x 128 B = 8 KB = one gl_lds16 per thread) double-buffered;
// per tile: stage(t+1) -> vmcnt(1) -> s_barrier -> 2 steps of
// {ds_read_b128 + 11 named-accumulator masked FMAs} -> s_barrier.
// ---------------------------------------------------------------------------
__global__ __launch_bounds__(512, 8) void main_kernel(
    const float* __restrict__ logit, const int* __restrict__ target,
    const float* __restrict__ feats, float* __restrict__ ws)
{
    // byte map: [0,8K) labels (2048 i32) | [8K,16K) feat buf0 | [16K,24K) buf1
    // after the tile loop, [0,21.5K) is re-purposed as s_part[8][8][21] f4.
    __shared__ __align__(16) char smem[24 * 1024];
    __shared__ int   s_hist[C_CLS];
    __shared__ float s_red[8][4];
    __shared__ float s_ssq[8];

    int* s_lab = (int*)smem;

    const int tid   = threadIdx.x;
    const int img   = blockIdx.x >> 7;       // 128 blocks per image
    const int chunk = blockIdx.x & 127;
    const int wv    = tid >> 6;

    const float* fbase = feats + ((size_t)img * P_PIX + chunk * PX_BLK) * 32;

    if (tid < C_CLS) s_hist[tid] = 0;
    __syncthreads();

    // Prologue: stage feature tile 0 into buf0; completes during Phase A
    // (Phase A's trailing __syncthreads drains vmcnt anyway).
    gl_lds16(fbase + (size_t)tid * 4, smem + 8192 + (size_t)(tid & ~63) * 16);

    // ---------------- Phase A: logit terms + histogram + label capture ----
    float ce = 0.f, vm = 0.f, var = 0.f, inter = 0.f;
    {
        const int pq = chunk * 512 + tid;                     // quad index
        const int4 t = ((const int4*)target)[(size_t)img * PQ + pq];
        ((int4*)s_lab)[tid] = t;                              // labels for B
        const float4* lp = (const float4*)logit + (size_t)img * C_CLS * PQ + pq;

        float4 s  = {0.f, 0.f, 0.f, 0.f};
        float4 sc = {0.f, 0.f, 0.f, 0.f};
        float4 lg = {0.f, 0.f, 0.f, 0.f};

#define LOADX(i) const float4 x##i = lp[(size_t)(i) * PQ];
        LOADX(0)  LOADX(1)  LOADX(2)  LOADX(3)  LOADX(4)  LOADX(5)  LOADX(6)
        LOADX(7)  LOADX(8)  LOADX(9)  LOADX(10) LOADX(11) LOADX(12) LOADX(13)
        LOADX(14) LOADX(15) LOADX(16) LOADX(17) LOADX(18) LOADX(19) LOADX(20)
#undef LOADX

#define CONS(i) { const float4 v = x##i;                                   \
        s.x += __expf(v.x); s.y += __expf(v.y);                            \
        s.z += __expf(v.z); s.w += __expf(v.w);                            \
        sc.x += v.x; sc.y += v.y; sc.z += v.z; sc.w += v.w;                \
        lg.x = (t.x == (i)) ? v.x : lg.x;                                  \
        lg.y = (t.y == (i)) ? v.y : lg.y;                                  \
        lg.z = (t.z == (i)) ? v.z : lg.z;                                  \
        lg.w = (t.w == (i)) ? v.w : lg.w; }
        CONS(0)  CONS(1)  CONS(2)  CONS(3)  CONS(4)  CONS(5)  CONS(6)
        CONS(7)  CONS(8)  CONS(9)  CONS(10) CONS(11) CONS(12) CONS(13)
        CONS(14) CONS(15) CONS(16) CONS(17) CONS(18) CONS(19) CONS(20)
#undef CONS

        if (t.x != IGN) atomicAdd(&s_hist[t.x], 1);
        if (t.y != IGN) atomicAdd(&s_hist[t.y], 1);
        if (t.z != IGN) atomicAdd(&s_hist[t.z], 1);
        if (t.w != IGN) atomicAdd(&s_hist[t.w], 1);

        {
            const float v = (t.x != IGN) ? 1.f : 0.f;
            vm += v; ce += v * (__logf(s.x) - lg.x); var -= v * lg.x; inter += v * (sc.x - lg.x);
        }
        {
            const float v = (t.y != IGN) ? 1.f : 0.f;
            vm += v; ce += v * (__logf(s.y) - lg.y); var -= v * lg.y; inter += v * (sc.y - lg.y);
        }
        {
            const float v = (t.z != IGN) ? 1.f : 0.f;
            vm += v; ce += v * (__logf(s.z) - lg.z); var -= v * lg.z; inter += v * (sc.z - lg.z);
        }
        {
            const float v = (t.w != IGN) ? 1.f : 0.f;
            vm += v; ce += v * (__logf(s.w) - lg.w); var -= v * lg.w; inter += v * (sc.w - lg.w);
        }
    }

    for (int off = 32; off; off >>= 1) {
        ce    += __shfl_xor(ce, off);
        vm    += __shfl_xor(vm, off);
        var   += __shfl_xor(var, off);
        inter += __shfl_xor(inter, off);
    }
    if ((tid & 63) == 0) {
        s_red[wv][0] = ce; s_red[wv][1] = vm; s_red[wv][2] = var; s_red[wv][3] = inter;
    }
    __syncthreads();   // orders histogram atomics + s_lab writes + s_red
                       // (also drains the tile-0 stage; harmless)

    // ---------------- Phase B: center-loss class sums ---------------------
    const int half = tid & 1;            // even/odd class half
    const int dg   = (tid >> 1) & 7;     // dim group 0..7 (float4 within row)
    const int pxg  = tid >> 4;           // 0..31: pixel within step

#define DEFACC(k) float4 a##k = {0.f, 0.f, 0.f, 0.f};
    DEFACC(0) DEFACC(1) DEFACC(2) DEFACC(3) DEFACC(4) DEFACC(5)
    DEFACC(6) DEFACC(7) DEFACC(8) DEFACC(9) DEFACC(10)
#undef DEFACC
    float ssq = 0.f;

#pragma unroll 1
    for (int tt = 0; tt < NT; ++tt) {
        const float* cur = (const float*)(smem + 8192 + (size_t)(tt & 1) * 8192);
        if (tt + 1 < NT) {
            gl_lds16(fbase + (size_t)(tt + 1) * TILE_PX * 32 + (size_t)tid * 4,
                     smem + 8192 + (size_t)((tt + 1) & 1) * 8192
                          + (size_t)(tid & ~63) * 16);
            // wait for tile tt's stage; leave tile tt+1's in flight
            asm volatile("s_waitcnt vmcnt(1)" ::: "memory");
        } else {
            asm volatile("s_waitcnt vmcnt(0)" ::: "memory");
        }
        __builtin_amdgcn_sched_barrier(0);
        __builtin_amdgcn_s_barrier();      // all waves' stage(tt) complete
        __builtin_amdgcn_sched_barrier(0);

#pragma unroll
        for (int h = 0; h < 2; ++h) {
            const int px  = h * 32 + pxg;
            const int lab = s_lab[tt * TILE_PX + px];
            const float4 f = ((const float4*)cur)[px * 8 + dg];
            const int labh = lab - half;   // labh==2k  <=>  lab==2k+half
            const float vss = (half == 0 && lab != IGN) ? 1.f : 0.f;
            ssq += vss * (f.x * f.x + f.y * f.y + f.z * f.z + f.w * f.w);
#define STEP(k) { const float m = (labh == (2 * (k))) ? 1.f : 0.f;         \
            a##k.x += m * f.x; a##k.y += m * f.y;                          \
            a##k.z += m * f.z; a##k.w += m * f.w; }
            STEP(0) STEP(1) STEP(2) STEP(3) STEP(4) STEP(5)
            STEP(6) STEP(7) STEP(8) STEP(9) STEP(10)
#undef STEP
        }
        __builtin_amdgcn_sched_barrier(0);
        __builtin_amdgcn_s_barrier();      // buffer-reuse guard
    }

    __syncthreads();                       // drain; smem re-purposed below

    // reduce across the 4 px-lanes (lane bits 4,5) sharing (half, dg)
#define REDACC(k)                                                          \
    a##k.x += __shfl_xor(a##k.x, 16); a##k.x += __shfl_xor(a##k.x, 32);    \
    a##k.y += __shfl_xor(a##k.y, 16); a##k.y += __shfl_xor(a##k.y, 32);    \
    a##k.z += __shfl_xor(a##k.z, 16); a##k.z += __shfl_xor(a##k.z, 32);    \
    a##k.w += __shfl_xor(a##k.w, 16); a##k.w += __shfl_xor(a##k.w, 32);
    REDACC(0) REDACC(1) REDACC(2) REDACC(3) REDACC(4) REDACC(5)
    REDACC(6) REDACC(7) REDACC(8) REDACC(9) REDACC(10)
#undef REDACC
    for (int off = 1; off < 64; off <<= 1) ssq += __shfl_xor(ssq, off);

    float4* s_part = (float4*)smem;        // [8][8][21], aliases lab+buffers
    if ((tid & 48) == 0) {                 // 16 writer lanes per wave
        const int pbase = (wv * 8 + dg) * C_CLS;
#define STORE(k) s_part[pbase + 2 * (k) + half] = a##k;
        STORE(0) STORE(1) STORE(2) STORE(3) STORE(4) STORE(5)
        STORE(6) STORE(7) STORE(8) STORE(9)
        if (half == 0) { STORE(10) }       // class 21 doesn't exist
#undef STORE
    }
    if ((tid & 63) == 0) s_ssq[wv] = ssq;
    __syncthreads();

    // ---------------- epilogue: all global writes ------------------------
    if (tid < 4) {
        float r = 0.f;
#pragma unroll
        for (int w = 0; w < 8; ++w) r += s_red[w][tid];
        ws[OFF_PIX + blockIdx.x * 4 + tid] = r;
    }
    if (tid < C_CLS) {
        ((int*)ws)[OFF_CNT + blockIdx.x * C_CLS + tid] = s_hist[tid];
    }
    if (tid < C_CLS * 8) {                 // 168 threads: one float4 each
        const int c = tid >> 3, g = tid & 7;
        float4 v = {0.f, 0.f, 0.f, 0.f};
#pragma unroll
        for (int w = 0; w < 8; ++w) {
            const float4 p = s_part[(w * 8 + g) * C_CLS + c];
            v.x += p.x; v.y += p.y; v.z += p.z; v.w += p.w;
        }
        // float offset: blk*672 + c*32 + g*4  (matches reduce_kernel)
        ((float4*)(ws + OFF_CLS))[(size_t)blockIdx.x * 168 + tid] = v;
    }
    if (tid == 0) {
        float r = 0.f;
#pragma unroll
        for (int w = 0; w < 8; ++w) r += s_ssq[w];
        ws[OFF_SSQ + blockIdx.x] = r;
    }
}

// ---------------------------------------------------------------------------
// Kernel 2: fold class-sum partials + count partials into 168 mean-terms.
// One block per (img, class). 128 threads.
// ---------------------------------------------------------------------------
__global__ __launch_bounds__(128) void reduce_kernel(float* __restrict__ ws)
{
    __shared__ float sred[128];
    __shared__ int   s_cnt;

    const int img = blockIdx.x / C_CLS;
    const int c   = blockIdx.x % C_CLS;
    const int tid = threadIdx.x;
    const int d   = tid & 31;         // dim
    const int qq  = tid >> 5;         // 0..3

    if (tid == 0) s_cnt = 0;
    __syncthreads();

    // counts: sum this image's 128 block histograms (one per thread)
    {
        const int* cp = (const int*)ws + OFF_CNT;
        const int cnt = cp[(img * 128 + tid) * C_CLS + c];
        atomicAdd(&s_cnt, cnt);
    }

    // class sums: sum this image's 128 block partials for (c, d)
    float s = 0.f;
    for (int b = qq; b < 128; b += 4)
        s += ws[OFF_CLS + (size_t)(img * 128 + b) * 672 + c * 32 + d];
    sred[tid] = s;
    __syncthreads();                  // also orders s_cnt atomics
    if (tid < 64) sred[tid] += sred[tid + 64];
    __syncthreads();
    if (tid < 32) {
        const float Sd = sred[tid] + sred[tid + 32];
        float n2 = Sd * Sd;
        for (int off = 1; off < 32; off <<= 1) n2 += __shfl_xor(n2, off);
        if (tid == 0)
            ws[OFF_MEAN + blockIdx.x] = n2 / fmaxf((float)s_cnt, 1.f);
    }
}

// ---------------------------------------------------------------------------
// Kernel 3: final combine.
// ---------------------------------------------------------------------------
__global__ __launch_bounds__(256) void finalize_kernel(
    const float* __restrict__ ws, float* __restrict__ out)
{
    __shared__ float fr[4][6];
    const int tid = threadIdx.x;

    float ce = 0.f, vm = 0.f, var = 0.f, inter = 0.f, ssq = 0.f, mean = 0.f;
    for (int b = tid; b < MAIN_BLOCKS; b += 256) {
        const float* p = ws + OFF_PIX + b * 4;
        ce += p[0]; vm += p[1]; var += p[2]; inter += p[3];
        ssq += ws[OFF_SSQ + b];
    }
    if (tid < N_IMG * C_CLS) mean = ws[OFF_MEAN + tid];

    for (int off = 32; off; off >>= 1) {
        ce   += __shfl_xor(ce, off);   vm    += __shfl_xor(vm, off);
        var  += __shfl_xor(var, off);  inter += __shfl_xor(inter, off);
        ssq  += __shfl_xor(ssq, off);  mean  += __shfl_xor(mean, off);
    }
    const int wv = tid >> 6;
    if ((tid & 63) == 0) {
        fr[wv][0] = ce;  fr[wv][1] = vm;   fr[wv][2] = var;
        fr[wv][3] = inter; fr[wv][4] = ssq; fr[wv][5] = mean;
    }
    __syncthreads();
    if (tid == 0) {
        const float CE_s  = fr[0][0] + fr[1][0] + fr[2][0] + fr[3][0];
        const float VM    = fr[0][1] + fr[1][1] + fr[2][1] + fr[3][1];
        const float VAR_s = fr[0][2] + fr[1][2] + fr[2][2] + fr[3][2];
        const float INT_s = fr[0][3] + fr[1][3] + fr[2][3] + fr[3][3];
        const float SSQ   = fr[0][4] + fr[1][4] + fr[2][4] + fr[3][4];
        const float MEAN  = fr[0][5] + fr[1][5] + fr[2][5] + fr[3][5];
        const float invP   = 1.f / (float)P_PIX;
        const float CE     = CE_s / fmaxf(VM, 1.f);
        const float VAR    = VAR_s * invP;
        const float Inter  = INT_s * invP;
        const float Center = (SSQ - MEAN) * invP;
        out[0] = (CE + ALPHA * VAR + BETA * Inter + GAMMA * Center) / (float)N_IMG;
    }
}

extern "C" void kernel_launch(void* const* d_in, const int* in_sizes, int n_in,
                              void* d_out, int out_size, void* d_ws, size_t ws_size,
                              hipStream_t stream)
{
    const float* logit  = (const float*)d_in[0];
    const int*   target = (const int*)d_in[1];
    const float* feats  = (const float*)d_in[2];
    float* ws  = (float*)d_ws;
    float* out = (float*)d_out;

    // No memset needed: every ws word consumed is written earlier in-stream.
    main_kernel    <<<MAIN_BLOCKS, 512, 0, stream>>>(logit, target, feats, ws);
    reduce_kernel  <<<N_IMG * C_CLS, 128, 0, stream>>>(ws);
    finalize_kernel<<<1, 256, 0, stream>>>(ws, out);
}